// Round 2
// baseline (1661.933 us; speedup 1.0000x reference)
//
#include <hip/hip_runtime.h>
#include <hip/hip_bf16.h>

#define B_ 4
#define T_ 4096
#define D_ 1024
#define R_ (B_*T_)
#define NB_ 16
#define RANK_ 64
#define NMEM_ 128
#define CHUNK_ 256
#define NCH_ (T_/CHUNK_)
#define EPS_ 1.1920929e-07f

__device__ __forceinline__ float silu_f(float v){ return v / (1.0f + expf(-v)); }

// ---------------- setup: a_seq, a_seq^CHUNK, depth gain ----------------
__global__ void setup_k(const float* __restrict__ logA_seq, const float* __restrict__ logdt_seq,
                        const float* __restrict__ logA_dep, const float* __restrict__ logdt_dep,
                        const int* __restrict__ active_k,
                        float* __restrict__ aseq, float* __restrict__ apowC, float* __restrict__ gain){
    int d = blockIdx.x*blockDim.x + threadIdx.x;
    if (d >= D_) return;
    float K = (float)(*active_k);
    float a = expf(-expf(logA_seq[d]) * expf(logdt_seq[d]));
    a = fmaxf(a, 1e-6f);
    aseq[d] = a;
    apowC[d] = powf(a, (float)CHUNK_);
    float g;
    if (d < NMEM_) {
        g = K;
    } else {
        float ad = expf(-expf(logA_dep[d-NMEM_]) * expf(logdt_dep[d-NMEM_]));
        float om = 1.0f - ad;
        if (fabsf(om) < 1e-6f) g = K;
        else g = (1.0f - powf(ad, K)) / fmaxf(om, 1e-8f);
    }
    gain[d] = g;
}

// ---------------- rms_norm rows (also used in-place on h) ----------------
__global__ __launch_bounds__(256) void rms_k(const float* __restrict__ x, float* __restrict__ e){
    int row = blockIdx.x;
    int tid = threadIdx.x;
    const float4* xr = (const float4*)(x + (size_t)row*D_);
    float4 v = xr[tid];
    float ss = v.x*v.x + v.y*v.y + v.z*v.z + v.w*v.w;
    for (int off=32; off; off>>=1) ss += __shfl_down(ss, off, 64);
    __shared__ float red[4];
    if ((tid&63)==0) red[tid>>6] = ss;
    __syncthreads();
    float tot = red[0]+red[1]+red[2]+red[3];
    float scale = 1.0f / sqrtf(tot*(1.0f/D_) + EPS_);
    float4 o; o.x=v.x*scale; o.y=v.y*scale; o.z=v.z*scale; o.w=v.w*scale;
    ((float4*)(e + (size_t)row*D_))[tid] = o;
}

// ---------------- blockdiag 64x64, SGPR-broadcast weights, row-per-lane ----------------
// out[row][n*64+j] = act( sum_i e[row][n*64+i] * w[n][j][i] ),  act = silu (xgain if gain!=null)
__global__ __launch_bounds__(256) void bd_k(const float* __restrict__ e, const float* __restrict__ w,
                                            const float* __restrict__ gain, float* __restrict__ out){
    __shared__ float T[4][64][17];
    int wave = threadIdx.x >> 6, lane = threadIdx.x & 63;
    int n  = blockIdx.y;
    int r0 = (blockIdx.x*4 + wave)*64;
    int row = r0 + lane;
    const float* erow = e + (size_t)row*D_ + n*64;
    float acc[64];
    #pragma unroll
    for (int j=0;j<64;++j) acc[j]=0.f;
    #pragma unroll 1
    for (int kt=0; kt<2; ++kt){
        float er[32];
        const float4* p = (const float4*)(erow + kt*32);
        #pragma unroll
        for (int q=0;q<8;++q){ float4 v=p[q]; er[4*q]=v.x; er[4*q+1]=v.y; er[4*q+2]=v.z; er[4*q+3]=v.w; }
        const float* wb = w + n*4096 + kt*32;          // wave-uniform -> s_load
        #pragma unroll
        for (int j=0;j<64;++j){
            float a = acc[j];
            const float* wj = wb + j*64;
            #pragma unroll
            for (int i=0;i<32;++i) a = fmaf(wj[i], er[i], a);
            acc[j]=a;
        }
    }
    float* dst = out + (size_t)r0*D_ + n*64;
    #pragma unroll 1
    for (int jc=0;jc<4;++jc){
        #pragma unroll
        for (int jj=0;jj<16;++jj){
            float v = silu_f(acc[jc*16+jj]);
            if (gain) v *= gain[n*64 + jc*16 + jj];
            T[wave][lane][jj] = v;
        }
        #pragma unroll
        for (int g=0; g<16; ++g){
            int rr = g*4 + (lane>>4);
            int c  = lane & 15;
            dst[(size_t)rr*D_ + jc*16 + c] = T[wave][rr][c];
        }
    }
}

// ---------------- scan passes (unchanged, coalesced, memory-bound) ----------------
__global__ __launch_bounds__(256) void scan1_k(float* __restrict__ h, const float* __restrict__ aseq,
                                               float* __restrict__ carry){
    int tid = blockIdx.x*256 + threadIdx.x;
    int d  = tid & (D_-1);
    int bc = tid >> 10;
    int c  = bc & (NCH_-1);
    int b  = bc >> 4;
    float a = aseq[d];
    size_t base = ((size_t)(b*T_ + c*CHUNK_))*D_ + d;
    float hh = 0.f;
    for (int s=0; s<CHUNK_; ++s){
        float v = h[base + (size_t)s*D_];
        hh = a*hh + v;
        h[base + (size_t)s*D_] = hh;
    }
    carry[(size_t)bc*D_ + d] = hh;
}

__global__ __launch_bounds__(256) void scan2_k(float* __restrict__ carry, const float* __restrict__ apowC){
    int tid = blockIdx.x*256 + threadIdx.x;
    int d = tid & (D_-1);
    int b = tid >> 10;
    float aC = apowC[d];
    float pref = 0.f;
    for (int c=0;c<NCH_;++c){
        size_t idx = (size_t)(b*NCH_+c)*D_ + d;
        float s = carry[idx];
        carry[idx] = pref;
        pref = aC*pref + s;
    }
}

__global__ __launch_bounds__(256) void scan3_k(float* __restrict__ h, const float* __restrict__ hdep,
                                               const float* __restrict__ aseq, const float* __restrict__ carry){
    int tid = blockIdx.x*256 + threadIdx.x;
    int d  = tid & (D_-1);
    int bc = tid >> 10;
    float a = aseq[d];
    float P = carry[(size_t)bc*D_ + d];
    int c  = bc & (NCH_-1);
    int b  = bc >> 4;
    size_t base = ((size_t)(b*T_ + c*CHUNK_))*D_ + d;
    float apow = a;
    for (int s=0;s<CHUNK_;++s){
        size_t idx = base + (size_t)s*D_;
        h[idx] = h[idx] + P*apow + hdep[idx];
        apow *= a;
    }
}

// ---------------- post: r = silu(blockdiag(concat[hn, e, eshift], w_post)), K=192 ----------------
__global__ __launch_bounds__(256) void post_k(const float* __restrict__ hn, const float* __restrict__ e,
                                              const float* __restrict__ w, float* __restrict__ rout){
    __shared__ float T[4][64][17];
    int wave=threadIdx.x>>6, lane=threadIdx.x&63;
    int n  = blockIdx.y;
    int r0 = (blockIdx.x*4+wave)*64;
    int row = r0 + lane;
    float acc[64];
    #pragma unroll
    for (int j=0;j<64;++j) acc[j]=0.f;
    #pragma unroll 1
    for (int kt=0; kt<6; ++kt){
        int g0 = n*192 + kt*32;
        const float* src;
        bool shiftz = false;
        if (g0 < 1024)      { src = hn + (size_t)row*D_ + g0; }
        else if (g0 < 2048) { src = e  + (size_t)row*D_ + (g0-1024); }
        else                { src = e  + ((size_t)row-1)*D_ + (g0-2048); shiftz = ((row & (T_-1))==0); }
        float er[32];
        if (shiftz){
            #pragma unroll
            for (int i=0;i<32;++i) er[i]=0.f;
        } else {
            const float4* p=(const float4*)src;
            #pragma unroll
            for (int q=0;q<8;++q){ float4 v=p[q]; er[4*q]=v.x; er[4*q+1]=v.y; er[4*q+2]=v.z; er[4*q+3]=v.w; }
        }
        const float* wb = w + n*64*192 + kt*32;
        #pragma unroll
        for (int j=0;j<64;++j){
            float a=acc[j];
            const float* wj = wb + (size_t)j*192;
            #pragma unroll
            for (int i=0;i<32;++i) a = fmaf(wj[i], er[i], a);
            acc[j]=a;
        }
    }
    float* dst = rout + (size_t)r0*D_ + n*64;
    #pragma unroll 1
    for (int jc=0;jc<4;++jc){
        #pragma unroll
        for (int jj=0;jj<16;++jj) T[wave][lane][jj] = silu_f(acc[jc*16+jj]);
        #pragma unroll
        for (int g=0; g<16; ++g){
            int rr = g*4 + (lane>>4);
            int c  = lane & 15;
            dst[(size_t)rr*D_ + jc*16 + c] = T[wave][rr][c];
        }
    }
}

// ---------------- outA: partial rlow[ks][row][k] = sum_{i in ks-slice} r[row][i]*lrB[k][i] ----------------
__global__ __launch_bounds__(256) void outA_k(const float* __restrict__ r, const float* __restrict__ lrB,
                                              float* __restrict__ partial){
    __shared__ float T[4][64][17];
    int wave=threadIdx.x>>6, lane=threadIdx.x&63;
    int ks = blockIdx.y;               // 0..7, each 128 of K=1024
    int r0 = (blockIdx.x*4+wave)*64;
    int row = r0+lane;
    float acc[64];
    #pragma unroll
    for (int k=0;k<64;++k) acc[k]=0.f;
    #pragma unroll 1
    for (int kt=0; kt<4; ++kt){
        int i0 = ks*128 + kt*32;
        float er[32];
        const float4* p=(const float4*)(r + (size_t)row*D_ + i0);
        #pragma unroll
        for (int q=0;q<8;++q){ float4 v=p[q]; er[4*q]=v.x; er[4*q+1]=v.y; er[4*q+2]=v.z; er[4*q+3]=v.w; }
        #pragma unroll
        for (int k=0;k<64;++k){
            float a=acc[k];
            const float* wj = lrB + (size_t)k*1024 + i0;   // lrB[k][i], wave-uniform
            #pragma unroll
            for (int i=0;i<32;++i) a = fmaf(wj[i], er[i], a);
            acc[k]=a;
        }
    }
    float* dst = partial + ((size_t)ks*R_ + r0)*64;
    #pragma unroll 1
    for (int jc=0;jc<4;++jc){
        #pragma unroll
        for (int jj=0;jj<16;++jj) T[wave][lane][jj]=acc[jc*16+jj];
        #pragma unroll
        for (int g=0;g<16;++g){
            int rr=g*4+(lane>>4), c=lane&15;
            dst[(size_t)rr*64 + jc*16 + c] = T[wave][rr][c];
        }
    }
}

__global__ void outA2_k(const float* __restrict__ partial, float* __restrict__ rlow){
    size_t idx = (size_t)blockIdx.x*256 + threadIdx.x;   // over R_*64
    float s=0.f;
    #pragma unroll
    for (int p=0;p<8;++p) s += partial[(size_t)p*R_*64 + idx];
    rlow[idx]=s;
}

// ---------------- outB: out = x + blockdiag(r,w_local) + rlow @ lrA^T ----------------
__global__ __launch_bounds__(256) void outB_k(const float* __restrict__ x, const float* __restrict__ r,
        const float* __restrict__ rlow, const float* __restrict__ wloc, const float* __restrict__ lrA,
        float* __restrict__ out){
    __shared__ float T[4][64][17];
    int wave=threadIdx.x>>6, lane=threadIdx.x&63;
    int n = blockIdx.y;
    int r0=(blockIdx.x*4+wave)*64;
    int row=r0+lane;
    float rl[64];
    {
        const float4* p=(const float4*)(rlow + (size_t)row*64);
        #pragma unroll
        for (int q=0;q<16;++q){ float4 v=p[q]; rl[4*q]=v.x; rl[4*q+1]=v.y; rl[4*q+2]=v.z; rl[4*q+3]=v.w; }
    }
    float* dst = out + (size_t)r0*D_ + n*64;
    const float* xb = x + (size_t)r0*D_ + n*64;
    #pragma unroll 1
    for (int jc=0;jc<4;++jc){
        float acc[16];
        #pragma unroll
        for (int jj=0;jj<16;++jj) acc[jj]=0.f;
        const float* ab = lrA + (size_t)(n*64 + jc*16)*64;   // lrA[o][k], wave-uniform
        #pragma unroll
        for (int jj=0;jj<16;++jj){
            float a=acc[jj];
            const float* aj = ab + jj*64;
            #pragma unroll
            for (int k=0;k<64;++k) a = fmaf(aj[k], rl[k], a);
            acc[jj]=a;
        }
        #pragma unroll 1
        for (int kt=0;kt<2;++kt){
            float er[32];
            const float4* p=(const float4*)(r + (size_t)row*D_ + n*64 + kt*32);
            #pragma unroll
            for (int q=0;q<8;++q){ float4 v=p[q]; er[4*q]=v.x; er[4*q+1]=v.y; er[4*q+2]=v.z; er[4*q+3]=v.w; }
            const float* wb = wloc + n*4096 + (jc*16)*64 + kt*32;  // wloc[n][j][i]
            #pragma unroll
            for (int jj=0;jj<16;++jj){
                float a=acc[jj];
                const float* wj = wb + jj*64;
                #pragma unroll
                for (int i=0;i<32;++i) a = fmaf(wj[i], er[i], a);
                acc[jj]=a;
            }
        }
        #pragma unroll
        for (int jj=0;jj<16;++jj) T[wave][lane][jj]=acc[jj];
        #pragma unroll
        for (int g=0;g<16;++g){
            int rr=g*4+(lane>>4), c=lane&15;
            dst[(size_t)rr*D_ + jc*16 + c] = xb[(size_t)rr*D_ + jc*16 + c] + T[wave][rr][c];
        }
    }
}

extern "C" void kernel_launch(void* const* d_in, const int* in_sizes, int n_in,
                              void* d_out, int out_size, void* d_ws, size_t ws_size,
                              hipStream_t stream) {
    const float* x         = (const float*)d_in[0];
    const int*   active_k  = (const int*)  d_in[1];
    const float* b_seq_w   = (const float*)d_in[2];
    const float* b_depth_w = (const float*)d_in[3];
    const float* w_post_w  = (const float*)d_in[4];
    const float* w_local_w = (const float*)d_in[5];
    const float* lr_A      = (const float*)d_in[6];
    const float* lr_B      = (const float*)d_in[7];
    const float* logA_seq  = (const float*)d_in[8];
    const float* logdt_seq = (const float*)d_in[9];
    const float* logA_dep  = (const float*)d_in[10];
    const float* logdt_dep = (const float*)d_in[11];

    float* ws = (float*)d_ws;
    float* e      = ws;                          // R_*D_
    float* h      = e + (size_t)R_*D_;           // R_*D_
    float* rbuf   = h + (size_t)R_*D_;           // R_*D_ (hdep, then r)
    float* carry  = rbuf + (size_t)R_*D_;        // B_*NCH_*D_
    float* aseq   = carry + (size_t)B_*NCH_*D_;
    float* apowC  = aseq + D_;
    float* gain   = apowC + D_;
    // after post_k, e is dead -> reuse for low-rank partials + rlow
    float* partial = e;                          // 8*R_*64 = 8.39M floats (< R_*D_)
    float* rlow    = e + (size_t)8*R_*64;        // R_*64

    setup_k<<<4, 256, 0, stream>>>(logA_seq, logdt_seq, logA_dep, logdt_dep, active_k,
                                   aseq, apowC, gain);
    rms_k  <<<R_, 256, 0, stream>>>(x, e);
    bd_k   <<<dim3(64,16), 256, 0, stream>>>(e, b_seq_w,   nullptr, h);     // drive
    bd_k   <<<dim3(64,16), 256, 0, stream>>>(e, b_depth_w, gain,    rbuf);  // h_depth
    scan1_k<<<(B_*NCH_*D_)/256, 256, 0, stream>>>(h, aseq, carry);
    scan2_k<<<(B_*D_)/256, 256, 0, stream>>>(carry, apowC);
    scan3_k<<<(B_*NCH_*D_)/256, 256, 0, stream>>>(h, rbuf, aseq, carry);
    rms_k  <<<R_, 256, 0, stream>>>(h, h);                                  // hn in place
    post_k <<<dim3(64,16), 256, 0, stream>>>(h, e, w_post_w, rbuf);         // r
    outA_k <<<dim3(64,8), 256, 0, stream>>>(rbuf, lr_B, partial);
    outA2_k<<<(R_*64)/256, 256, 0, stream>>>(partial, rlow);
    outB_k <<<dim3(64,16), 256, 0, stream>>>(x, rbuf, rlow, w_local_w, lr_A, (float*)d_out);
}

// Round 3
// 392.511 us; speedup vs baseline: 4.2341x; 4.2341x over previous
//
#include <hip/hip_runtime.h>

#define B_ 4
#define T_ 4096
#define D_ 1024
#define R_ (B_*T_)
#define CHUNK_ 256
#define NCH_ (T_/CHUNK_)
#define EPS_ 1.1920929e-07f

typedef unsigned short ushort_t;
typedef __attribute__((ext_vector_type(8))) short short8;
typedef __attribute__((ext_vector_type(4))) float f32x4;

__device__ __forceinline__ float silu_f(float v){ return v / (1.0f + expf(-v)); }

__device__ __forceinline__ ushort_t f2bf(float f){
    unsigned u = __float_as_uint(f);
    unsigned r = u + 0x7fffu + ((u>>16)&1u);
    return (ushort_t)(r>>16);
}
__device__ __forceinline__ float bf2f(ushort_t s){ return __uint_as_float(((unsigned)s)<<16); }

__device__ __forceinline__ f32x4 mfma16(short8 a, short8 b, f32x4 c){
    return __builtin_amdgcn_mfma_f32_16x16x32_bf16(a, b, c, 0, 0, 0);
}

// ---------------- setup: a_seq, a_seq^CHUNK, depth gain ----------------
__global__ void setup_k(const float* __restrict__ logA_seq, const float* __restrict__ logdt_seq,
                        const float* __restrict__ logA_dep, const float* __restrict__ logdt_dep,
                        const int* __restrict__ active_k,
                        float* __restrict__ aseq, float* __restrict__ apowC, float* __restrict__ gain){
    int d = blockIdx.x*blockDim.x + threadIdx.x;
    if (d >= D_) return;
    float K = (float)(*active_k);
    float a = expf(-expf(logA_seq[d]) * expf(logdt_seq[d]));
    a = fmaxf(a, 1e-6f);
    aseq[d] = a;
    apowC[d] = powf(a, (float)CHUNK_);
    float g;
    if (d < 128) {
        g = K;
    } else {
        float ad = expf(-expf(logA_dep[d-128]) * expf(logdt_dep[d-128]));
        float om = 1.0f - ad;
        if (fabsf(om) < 1e-6f) g = K;
        else g = (1.0f - powf(ad, K)) / fmaxf(om, 1e-8f);
    }
    gain[d] = g;
}

// ---------------- fp32 -> bf16 convert ----------------
__global__ void cvt_k(const float* __restrict__ in, ushort_t* __restrict__ out, int n){
    int i = blockIdx.x*256 + threadIdx.x;
    if (i < n) out[i] = f2bf(in[i]);
}

// ---------------- rms_norm rows -> bf16 ----------------
__global__ __launch_bounds__(256) void rmsbf_k(const float* __restrict__ x, ushort_t* __restrict__ e){
    int row = blockIdx.x;
    int tid = threadIdx.x;
    float4 v = ((const float4*)(x + (size_t)row*D_))[tid];
    float ss = v.x*v.x + v.y*v.y + v.z*v.z + v.w*v.w;
    for (int off=32; off; off>>=1) ss += __shfl_down(ss, off, 64);
    __shared__ float red[4];
    if ((tid&63)==0) red[tid>>6] = ss;
    __syncthreads();
    float tot = red[0]+red[1]+red[2]+red[3];
    float scale = 1.0f / sqrtf(tot*(1.0f/D_) + EPS_);
    ushort4 o;
    o.x = f2bf(v.x*scale); o.y = f2bf(v.y*scale); o.z = f2bf(v.z*scale); o.w = f2bf(v.w*scale);
    ((ushort4*)(e + (size_t)row*D_))[tid] = o;
}

// ---------------- bd2: drive = silu(e@Wseq^T) [fp32], hdep = gain*silu(e@Wdep^T) [bf16] ----------------
__global__ __launch_bounds__(256) void bd2_k(const ushort_t* __restrict__ e,
        const ushort_t* __restrict__ wseq, const ushort_t* __restrict__ wdep,
        const float* __restrict__ gain,
        float* __restrict__ drive, ushort_t* __restrict__ hdep){
    int wave = threadIdx.x>>6, lane = threadIdx.x&63;
    int m = lane&15, quad = lane>>4;
    int r0 = (blockIdx.x*4 + wave)*16;
    #pragma unroll 1
    for (int nn=0; nn<4; ++nn){
        int n = blockIdx.y*4 + nn;
        f32x4 accs[4], accd[4];
        #pragma unroll
        for (int c=0;c<4;++c){ accs[c]=(f32x4)0.f; accd[c]=(f32x4)0.f; }
        const ushort_t* ab = e + (size_t)(r0+m)*D_ + n*64 + quad*8;
        #pragma unroll
        for (int s=0;s<2;++s){
            short8 a = *(const short8*)(ab + s*32);
            #pragma unroll
            for (int c=0;c<4;++c){
                short8 bs = *(const short8*)(wseq + n*4096 + (c*16+m)*64 + s*32 + quad*8);
                short8 bd = *(const short8*)(wdep + n*4096 + (c*16+m)*64 + s*32 + quad*8);
                accs[c] = mfma16(a, bs, accs[c]);
                accd[c] = mfma16(a, bd, accd[c]);
            }
        }
        #pragma unroll
        for (int c=0;c<4;++c){
            int col = n*64 + c*16 + m;
            float g = gain[col];
            #pragma unroll
            for (int r=0;r<4;++r){
                size_t row = (size_t)(r0 + quad*4 + r);
                drive[row*D_ + col] = silu_f(accs[c][r]);
                hdep [row*D_ + col] = f2bf(g * silu_f(accd[c][r]));
            }
        }
    }
}

// ---------------- scan passes (fp32, coalesced) ----------------
__global__ __launch_bounds__(256) void scan1_k(float* __restrict__ h, const float* __restrict__ aseq,
                                               float* __restrict__ carry){
    int tid = blockIdx.x*256 + threadIdx.x;
    int d  = tid & (D_-1);
    int bc = tid >> 10;
    int c  = bc & (NCH_-1);
    int b  = bc >> 4;
    float a = aseq[d];
    size_t base = ((size_t)(b*T_ + c*CHUNK_))*D_ + d;
    float hh = 0.f;
    for (int s=0; s<CHUNK_; ++s){
        float v = h[base + (size_t)s*D_];
        hh = a*hh + v;
        h[base + (size_t)s*D_] = hh;
    }
    carry[(size_t)bc*D_ + d] = hh;
}

__global__ __launch_bounds__(256) void scan2_k(float* __restrict__ carry, const float* __restrict__ apowC){
    int tid = blockIdx.x*256 + threadIdx.x;
    int d = tid & (D_-1);
    int b = tid >> 10;
    float aC = apowC[d];
    float pref = 0.f;
    for (int c=0;c<NCH_;++c){
        size_t idx = (size_t)(b*NCH_+c)*D_ + d;
        float s = carry[idx];
        carry[idx] = pref;
        pref = aC*pref + s;
    }
}

__global__ __launch_bounds__(256) void scan3_k(float* __restrict__ h, const ushort_t* __restrict__ hdep,
                                               const float* __restrict__ aseq, const float* __restrict__ carry){
    int tid = blockIdx.x*256 + threadIdx.x;
    int d  = tid & (D_-1);
    int bc = tid >> 10;
    float a = aseq[d];
    float P = carry[(size_t)bc*D_ + d];
    int c  = bc & (NCH_-1);
    int b  = bc >> 4;
    size_t base = ((size_t)(b*T_ + c*CHUNK_))*D_ + d;
    float apow = a;
    for (int s=0;s<CHUNK_;++s){
        size_t idx = base + (size_t)s*D_;
        h[idx] = h[idx] + P*apow + bf2f(hdep[idx]);
        apow *= a;
    }
}

// ---------------- post: r = silu(concat[hn,e,eshift] @ wpost^T) -> bf16 ----------------
__global__ __launch_bounds__(256) void post_k(const ushort_t* __restrict__ hn, const ushort_t* __restrict__ e,
                                              const ushort_t* __restrict__ wpost, ushort_t* __restrict__ rout){
    int wave = threadIdx.x>>6, lane = threadIdx.x&63;
    int m = lane&15, quad = lane>>4;
    int r0 = (blockIdx.x*4 + wave)*16;
    int row = r0 + m;
    bool zrow = ((row & (T_-1)) == 0);
    #pragma unroll 1
    for (int nn=0; nn<4; ++nn){
        int n = blockIdx.y*4 + nn;
        f32x4 acc[4];
        #pragma unroll
        for (int c=0;c<4;++c) acc[c]=(f32x4)0.f;
        #pragma unroll
        for (int s=0;s<6;++s){
            int g0 = n*192 + s*32;
            short8 a;
            if (g0 < 1024){
                a = *(const short8*)(hn + (size_t)row*D_ + g0 + quad*8);
            } else if (g0 < 2048){
                a = *(const short8*)(e + (size_t)row*D_ + (g0-1024) + quad*8);
            } else {
                if (zrow) a = short8{0,0,0,0,0,0,0,0};
                else      a = *(const short8*)(e + (size_t)(row-1)*D_ + (g0-2048) + quad*8);
            }
            #pragma unroll
            for (int c=0;c<4;++c){
                short8 b = *(const short8*)(wpost + n*(64*192) + (c*16+m)*192 + s*32 + quad*8);
                acc[c] = mfma16(a, b, acc[c]);
            }
        }
        #pragma unroll
        for (int c=0;c<4;++c){
            int col = n*64 + c*16 + m;
            #pragma unroll
            for (int r=0;r<4;++r)
                rout[(size_t)(r0 + quad*4 + r)*D_ + col] = f2bf(silu_f(acc[c][r]));
        }
    }
}

// ---------------- rlow = r @ lrB^T  (K=1024, 64 outputs) -> bf16 ----------------
__global__ __launch_bounds__(256) void rlow_k(const ushort_t* __restrict__ r, const ushort_t* __restrict__ lrB,
                                              ushort_t* __restrict__ rlow){
    int wave = threadIdx.x>>6, lane = threadIdx.x&63;
    int m = lane&15, quad = lane>>4;
    int r0 = (blockIdx.x*4 + wave)*16;
    f32x4 acc[4];
    #pragma unroll
    for (int c=0;c<4;++c) acc[c]=(f32x4)0.f;
    const ushort_t* ab = r + (size_t)(r0+m)*D_ + quad*8;
    #pragma unroll 4
    for (int s=0;s<32;++s){
        short8 a = *(const short8*)(ab + s*32);
        #pragma unroll
        for (int c=0;c<4;++c){
            short8 b = *(const short8*)(lrB + (c*16+m)*1024 + s*32 + quad*8);
            acc[c] = mfma16(a, b, acc[c]);
        }
    }
    #pragma unroll
    for (int c=0;c<4;++c){
        int col = c*16 + m;
        #pragma unroll
        for (int r2=0;r2<4;++r2)
            rlow[(size_t)(r0 + quad*4 + r2)*64 + col] = f2bf(acc[c][r2]);
    }
}

// ---------------- out = x + r@wloc^T + rlow@lrA^T ----------------
__global__ __launch_bounds__(256) void out_k(const float* __restrict__ x, const ushort_t* __restrict__ r,
        const ushort_t* __restrict__ rlow, const ushort_t* __restrict__ wloc, const ushort_t* __restrict__ lrA,
        float* __restrict__ out){
    int wave = threadIdx.x>>6, lane = threadIdx.x&63;
    int m = lane&15, quad = lane>>4;
    int r0 = (blockIdx.x*4 + wave)*16;
    short8 al0 = *(const short8*)(rlow + (size_t)(r0+m)*64 + quad*8);
    short8 al1 = *(const short8*)(rlow + (size_t)(r0+m)*64 + 32 + quad*8);
    #pragma unroll 1
    for (int nn=0; nn<4; ++nn){
        int n = blockIdx.y*4 + nn;
        f32x4 acc[4];
        #pragma unroll
        for (int c=0;c<4;++c) acc[c]=(f32x4)0.f;
        // low-rank part: K=64 over rank
        #pragma unroll
        for (int c=0;c<4;++c){
            short8 b0 = *(const short8*)(lrA + (size_t)(n*64 + c*16 + m)*64 + quad*8);
            short8 b1 = *(const short8*)(lrA + (size_t)(n*64 + c*16 + m)*64 + 32 + quad*8);
            acc[c] = mfma16(al0, b0, acc[c]);
            acc[c] = mfma16(al1, b1, acc[c]);
        }
        // blockdiag local part: K=64
        const ushort_t* ab = r + (size_t)(r0+m)*D_ + n*64 + quad*8;
        #pragma unroll
        for (int s=0;s<2;++s){
            short8 a = *(const short8*)(ab + s*32);
            #pragma unroll
            for (int c=0;c<4;++c){
                short8 b = *(const short8*)(wloc + n*4096 + (c*16+m)*64 + s*32 + quad*8);
                acc[c] = mfma16(a, b, acc[c]);
            }
        }
        #pragma unroll
        for (int c=0;c<4;++c){
            int col = n*64 + c*16 + m;
            #pragma unroll
            for (int r2=0;r2<4;++r2){
                size_t idx = (size_t)(r0 + quad*4 + r2)*D_ + col;
                out[idx] = x[idx] + acc[c][r2];
            }
        }
    }
}

extern "C" void kernel_launch(void* const* d_in, const int* in_sizes, int n_in,
                              void* d_out, int out_size, void* d_ws, size_t ws_size,
                              hipStream_t stream) {
    const float* x         = (const float*)d_in[0];
    const int*   active_k  = (const int*)  d_in[1];
    const float* b_seq_w   = (const float*)d_in[2];
    const float* b_depth_w = (const float*)d_in[3];
    const float* w_post_w  = (const float*)d_in[4];
    const float* w_local_w = (const float*)d_in[5];
    const float* lr_A      = (const float*)d_in[6];
    const float* lr_B      = (const float*)d_in[7];
    const float* logA_seq  = (const float*)d_in[8];
    const float* logdt_seq = (const float*)d_in[9];
    const float* logA_dep  = (const float*)d_in[10];
    const float* logdt_dep = (const float*)d_in[11];

    float* ws    = (float*)d_ws;
    float* h     = ws;                             // R_*D_ fp32 (drive, then h in place)
    float* carry = h + (size_t)R_*D_;              // B_*NCH_*D_
    float* aseq  = carry + (size_t)B_*NCH_*D_;
    float* apowC = aseq + D_;
    float* gain  = apowC + D_;
    ushort_t* ub       = (ushort_t*)(gain + D_);
    ushort_t* e_bf     = ub;                       // R_*D_
    ushort_t* hn_bf    = e_bf + (size_t)R_*D_;     // R_*D_
    ushort_t* hdep_bf  = hn_bf + (size_t)R_*D_;    // R_*D_
    ushort_t* r_bf     = hdep_bf + (size_t)R_*D_;  // R_*D_
    ushort_t* rlow_bf  = r_bf + (size_t)R_*D_;     // R_*64
    ushort_t* wseq_bf  = rlow_bf + (size_t)R_*64;  // 65536
    ushort_t* wdep_bf  = wseq_bf + 65536;
    ushort_t* wpost_bf = wdep_bf + 65536;          // 196608
    ushort_t* wloc_bf  = wpost_bf + 196608;        // 65536
    ushort_t* lrA_bf   = wloc_bf + 65536;          // 65536
    ushort_t* lrB_bf   = lrA_bf + 65536;           // 65536

    setup_k<<<4, 256, 0, stream>>>(logA_seq, logdt_seq, logA_dep, logdt_dep, active_k,
                                   aseq, apowC, gain);
    cvt_k<<<(65536+255)/256, 256, 0, stream>>>(b_seq_w,   wseq_bf,  65536);
    cvt_k<<<(65536+255)/256, 256, 0, stream>>>(b_depth_w, wdep_bf,  65536);
    cvt_k<<<(196608+255)/256,256, 0, stream>>>(w_post_w,  wpost_bf, 196608);
    cvt_k<<<(65536+255)/256, 256, 0, stream>>>(w_local_w, wloc_bf,  65536);
    cvt_k<<<(65536+255)/256, 256, 0, stream>>>(lr_A,      lrA_bf,   65536);
    cvt_k<<<(65536+255)/256, 256, 0, stream>>>(lr_B,      lrB_bf,   65536);

    rmsbf_k<<<R_, 256, 0, stream>>>(x, e_bf);
    bd2_k  <<<dim3(R_/64, 4), 256, 0, stream>>>(e_bf, wseq_bf, wdep_bf, gain, h, hdep_bf);
    scan1_k<<<(B_*NCH_*D_)/256, 256, 0, stream>>>(h, aseq, carry);
    scan2_k<<<(B_*D_)/256, 256, 0, stream>>>(carry, apowC);
    scan3_k<<<(B_*NCH_*D_)/256, 256, 0, stream>>>(h, hdep_bf, aseq, carry);
    rmsbf_k<<<R_, 256, 0, stream>>>(h, hn_bf);
    post_k <<<dim3(R_/64, 4), 256, 0, stream>>>(hn_bf, e_bf, wpost_bf, r_bf);
    rlow_k <<<R_/64, 256, 0, stream>>>(r_bf, lrB_bf, rlow_bf);
    out_k  <<<dim3(R_/64, 4), 256, 0, stream>>>(x, r_bf, rlow_bf, wloc_bf, lrA_bf, (float*)d_out);
}

// Round 4
// 357.165 us; speedup vs baseline: 4.6531x; 1.0990x over previous
//
#include <hip/hip_runtime.h>

#define B_ 4
#define T_ 4096
#define D_ 1024
#define R_ (B_*T_)
#define CHUNK_ 64
#define NCH_ (T_/CHUNK_)
#define EPS_ 1.1920929e-07f

typedef unsigned short ushort_t;
typedef __attribute__((ext_vector_type(8))) short short8;
typedef __attribute__((ext_vector_type(4))) float f32x4;

__device__ __forceinline__ float silu_f(float v){ return v / (1.0f + expf(-v)); }

__device__ __forceinline__ ushort_t f2bf(float f){
    unsigned u = __float_as_uint(f);
    unsigned r = u + 0x7fffu + ((u>>16)&1u);
    return (ushort_t)(r>>16);
}
__device__ __forceinline__ float bf2f(ushort_t s){ return __uint_as_float(((unsigned)s)<<16); }

__device__ __forceinline__ f32x4 mfma16(short8 a, short8 b, f32x4 c){
    return __builtin_amdgcn_mfma_f32_16x16x32_bf16(a, b, c, 0, 0, 0);
}

__device__ __forceinline__ short8 scale_bf8(short8 raw, float sc){
    short8 o;
    #pragma unroll
    for (int j=0;j<8;++j) o[j] = (short)f2bf(bf2f((ushort_t)raw[j]) * sc);
    return o;
}

// ---------------- setup ----------------
__global__ void setup_k(const float* __restrict__ logA_seq, const float* __restrict__ logdt_seq,
                        const float* __restrict__ logA_dep, const float* __restrict__ logdt_dep,
                        const int* __restrict__ active_k,
                        float* __restrict__ aseq, float* __restrict__ apowC, float* __restrict__ gain){
    int d = blockIdx.x*blockDim.x + threadIdx.x;
    if (d >= D_) return;
    float K = (float)(*active_k);
    float a = expf(-expf(logA_seq[d]) * expf(logdt_seq[d]));
    a = fmaxf(a, 1e-6f);
    aseq[d] = a;
    apowC[d] = powf(a, (float)CHUNK_);
    float g;
    if (d < 128) {
        g = K;
    } else {
        float ad = expf(-expf(logA_dep[d-128]) * expf(logdt_dep[d-128]));
        float om = 1.0f - ad;
        if (fabsf(om) < 1e-6f) g = K;
        else g = (1.0f - powf(ad, K)) / fmaxf(om, 1e-8f);
    }
    gain[d] = g;
}

// ---------------- all weights fp32->bf16 in one launch ----------------
__global__ void cvt6_k(const float* __restrict__ s0, const float* __restrict__ s1,
                       const float* __restrict__ s2, const float* __restrict__ s3,
                       const float* __restrict__ s4, const float* __restrict__ s5,
                       ushort_t* __restrict__ d0, ushort_t* __restrict__ d1,
                       ushort_t* __restrict__ d2, ushort_t* __restrict__ d3,
                       ushort_t* __restrict__ d4, ushort_t* __restrict__ d5){
    int i = blockIdx.x*256 + threadIdx.x;
    if      (i < 65536)   d0[i] = f2bf(s0[i]);
    else if (i < 131072)  d1[i-65536] = f2bf(s1[i-65536]);
    else if (i < 327680)  d2[i-131072] = f2bf(s2[i-131072]);
    else if (i < 393216)  d3[i-327680] = f2bf(s3[i-327680]);
    else if (i < 458752)  d4[i-393216] = f2bf(s4[i-393216]);
    else if (i < 524288)  d5[i-458752] = f2bf(s5[i-458752]);
}

// ---------------- rms_norm(x) -> e bf16 ----------------
__global__ __launch_bounds__(256) void rmsbf_k(const float* __restrict__ x, ushort_t* __restrict__ e){
    int row = blockIdx.x;
    int tid = threadIdx.x;
    float4 v = ((const float4*)(x + (size_t)row*D_))[tid];
    float ss = v.x*v.x + v.y*v.y + v.z*v.z + v.w*v.w;
    for (int off=32; off; off>>=1) ss += __shfl_down(ss, off, 64);
    __shared__ float red[4];
    if ((tid&63)==0) red[tid>>6] = ss;
    __syncthreads();
    float tot = red[0]+red[1]+red[2]+red[3];
    float scale = 1.0f / sqrtf(tot*(1.0f/D_) + EPS_);
    ushort4 o;
    o.x = f2bf(v.x*scale); o.y = f2bf(v.y*scale); o.z = f2bf(v.z*scale); o.w = f2bf(v.w*scale);
    ((ushort4*)(e + (size_t)row*D_))[tid] = o;
}

// ---------------- bd2: drive=silu(e@Wseq^T) bf16, hdep=gain*silu(e@Wdep^T) bf16 ----------------
// weight-stationary: one n per block, 16 B-frags in VGPRs, 4 row-tiles per wave
__global__ __launch_bounds__(256) void bd2_k(const ushort_t* __restrict__ e,
        const ushort_t* __restrict__ wseq, const ushort_t* __restrict__ wdep,
        const float* __restrict__ gain,
        ushort_t* __restrict__ drive, ushort_t* __restrict__ hdep){
    int wave = threadIdx.x>>6, lane = threadIdx.x&63;
    int m = lane&15, quad = lane>>4;
    int n = blockIdx.y;
    int rowbase = blockIdx.x*256 + wave*64;
    short8 bs[2][4], bd[2][4];
    #pragma unroll
    for (int s=0;s<2;++s)
        #pragma unroll
        for (int c=0;c<4;++c){
            bs[s][c] = *(const short8*)(wseq + n*4096 + (c*16+m)*64 + s*32 + quad*8);
            bd[s][c] = *(const short8*)(wdep + n*4096 + (c*16+m)*64 + s*32 + quad*8);
        }
    float g[4];
    #pragma unroll
    for (int c=0;c<4;++c) g[c] = gain[n*64 + c*16 + m];
    #pragma unroll
    for (int tile=0; tile<4; ++tile){
        int r0 = rowbase + tile*16;
        const ushort_t* ab = e + (size_t)(r0+m)*D_ + n*64 + quad*8;
        short8 a0 = *(const short8*)ab;
        short8 a1 = *(const short8*)(ab + 32);
        f32x4 accs[4], accd[4];
        #pragma unroll
        for (int c=0;c<4;++c){
            accs[c]=(f32x4)0.f; accd[c]=(f32x4)0.f;
            accs[c]=mfma16(a0, bs[0][c], accs[c]);
            accd[c]=mfma16(a0, bd[0][c], accd[c]);
            accs[c]=mfma16(a1, bs[1][c], accs[c]);
            accd[c]=mfma16(a1, bd[1][c], accd[c]);
        }
        #pragma unroll
        for (int c=0;c<4;++c){
            int col = n*64 + c*16 + m;
            #pragma unroll
            for (int r=0;r<4;++r){
                size_t row = (size_t)(r0 + quad*4 + r);
                drive[row*D_ + col] = f2bf(silu_f(accs[c][r]));
                hdep [row*D_ + col] = f2bf(g[c] * silu_f(accd[c][r]));
            }
        }
    }
}

// ---------------- scan1: chunk-final sums only (no h materialization) ----------------
__global__ __launch_bounds__(256) void scan1_k(const ushort_t* __restrict__ drive,
                                               const float* __restrict__ aseq,
                                               float* __restrict__ carry){
    int tid = blockIdx.x*256 + threadIdx.x;     // B_*NCH_*D_ threads
    int d  = tid & (D_-1);
    int bc = tid >> 10;
    int c  = bc & (NCH_-1);
    int b  = bc >> 6;
    float a = aseq[d];
    size_t base = ((size_t)(b*T_ + c*CHUNK_))*D_ + d;
    float hh = 0.f;
    #pragma unroll 4
    for (int s=0; s<CHUNK_; ++s)
        hh = fmaf(a, hh, bf2f(drive[base + (size_t)s*D_]));
    carry[(size_t)bc*D_ + d] = hh;
}

// ---------------- scan2: serial prefix over NCH_ chunk carries ----------------
__global__ __launch_bounds__(256) void scan2_k(float* __restrict__ carry, const float* __restrict__ apowC){
    int tid = blockIdx.x*256 + threadIdx.x;     // B_*D_ threads
    int d = tid & (D_-1);
    int b = tid >> 10;
    float aC = apowC[d];
    float pref = 0.f;
    for (int c=0;c<NCH_;++c){
        size_t idx = (size_t)(b*NCH_+c)*D_ + d;
        float s = carry[idx];
        carry[idx] = pref;
        pref = fmaf(aC, pref, s);
    }
}

// ---------------- scan3: recompute local scan + carry + hdep -> h bf16, rowsumsq ----------------
__global__ __launch_bounds__(256) void scan3_k(const ushort_t* __restrict__ drive,
                                               const ushort_t* __restrict__ hdep,
                                               const float* __restrict__ aseq,
                                               const float* __restrict__ carry,
                                               ushort_t* __restrict__ h,
                                               float* __restrict__ sumsq){
    int tid = blockIdx.x*256 + threadIdx.x;
    int d  = tid & (D_-1);
    int bc = tid >> 10;
    int c  = bc & (NCH_-1);
    int b  = bc >> 6;
    int lane = threadIdx.x & 63;
    float a = aseq[d];
    float hh = carry[(size_t)bc*D_ + d];
    size_t base = ((size_t)(b*T_ + c*CHUNK_))*D_ + d;
    int row0 = b*T_ + c*CHUNK_;
    for (int s=0; s<CHUNK_; ++s){
        size_t idx = base + (size_t)s*D_;
        hh = fmaf(a, hh, bf2f(drive[idx]));
        float hf = hh + bf2f(hdep[idx]);
        h[idx] = f2bf(hf);
        float ssq = hf*hf;
        for (int off=32; off; off>>=1) ssq += __shfl_down(ssq, off, 64);
        if (lane==0) atomicAdd(&sumsq[row0 + s], ssq);
    }
}

// ---------------- rowscale = rsqrt(mean(h^2)+eps) ----------------
__global__ void rowscale_k(const float* __restrict__ sumsq, float* __restrict__ rowscale){
    int i = blockIdx.x*256 + threadIdx.x;
    if (i < R_) rowscale[i] = rsqrtf(sumsq[i]*(1.0f/D_) + EPS_);
}

// ---------------- post: r = silu(concat[hn,e,eshift] @ wpost^T) bf16 ----------------
__global__ __launch_bounds__(256) void post_k(const ushort_t* __restrict__ h, const float* __restrict__ rowscale,
                                              const ushort_t* __restrict__ e,
                                              const ushort_t* __restrict__ wpost, ushort_t* __restrict__ rout){
    int wave = threadIdx.x>>6, lane = threadIdx.x&63;
    int m = lane&15, quad = lane>>4;
    int n = blockIdx.y;
    int rowbase = blockIdx.x*256 + wave*64;
    short8 bw[6][4];
    #pragma unroll
    for (int s=0;s<6;++s)
        #pragma unroll
        for (int c=0;c<4;++c)
            bw[s][c] = *(const short8*)(wpost + n*(64*192) + (c*16+m)*192 + s*32 + quad*8);
    #pragma unroll
    for (int tile=0; tile<4; ++tile){
        int r0 = rowbase + tile*16;
        int row = r0 + m;
        float sc = rowscale[row];
        bool zrow = ((row & (T_-1)) == 0);
        short8 af[6];
        #pragma unroll
        for (int s=0;s<6;++s){
            int g0 = n*192 + s*32;
            if (g0 < 1024){
                short8 raw = *(const short8*)(h + (size_t)row*D_ + g0 + quad*8);
                af[s] = scale_bf8(raw, sc);
            } else if (g0 < 2048){
                af[s] = *(const short8*)(e + (size_t)row*D_ + (g0-1024) + quad*8);
            } else {
                if (zrow) af[s] = short8{0,0,0,0,0,0,0,0};
                else      af[s] = *(const short8*)(e + (size_t)(row-1)*D_ + (g0-2048) + quad*8);
            }
        }
        f32x4 acc[4];
        #pragma unroll
        for (int c=0;c<4;++c) acc[c]=(f32x4)0.f;
        #pragma unroll
        for (int s=0;s<6;++s)
            #pragma unroll
            for (int c=0;c<4;++c)
                acc[c] = mfma16(af[s], bw[s][c], acc[c]);
        #pragma unroll
        for (int c=0;c<4;++c){
            int col = n*64 + c*16 + m;
            #pragma unroll
            for (int r=0;r<4;++r)
                rout[(size_t)(r0 + quad*4 + r)*D_ + col] = f2bf(silu_f(acc[c][r]));
        }
    }
}

// ---------------- rlow = r @ lrB^T (K=1024 -> 64) bf16 ----------------
__global__ __launch_bounds__(256) void rlow_k(const ushort_t* __restrict__ r, const ushort_t* __restrict__ lrB,
                                              ushort_t* __restrict__ rlow){
    int wave = threadIdx.x>>6, lane = threadIdx.x&63;
    int m = lane&15, quad = lane>>4;
    int r0 = (blockIdx.x*4 + wave)*16;
    f32x4 acc[4];
    #pragma unroll
    for (int c=0;c<4;++c) acc[c]=(f32x4)0.f;
    const ushort_t* ab = r + (size_t)(r0+m)*D_ + quad*8;
    #pragma unroll 4
    for (int s=0;s<32;++s){
        short8 a = *(const short8*)(ab + s*32);
        #pragma unroll
        for (int c=0;c<4;++c){
            short8 b = *(const short8*)(lrB + (c*16+m)*1024 + s*32 + quad*8);
            acc[c] = mfma16(a, b, acc[c]);
        }
    }
    #pragma unroll
    for (int c=0;c<4;++c){
        int col = c*16 + m;
        #pragma unroll
        for (int r2=0;r2<4;++r2)
            rlow[(size_t)(r0 + quad*4 + r2)*64 + col] = f2bf(acc[c][r2]);
    }
}

// ---------------- out = x + r@wloc^T + rlow@lrA^T ----------------
__global__ __launch_bounds__(256) void out_k(const float* __restrict__ x, const ushort_t* __restrict__ r,
        const ushort_t* __restrict__ rlow, const ushort_t* __restrict__ wloc, const ushort_t* __restrict__ lrA,
        float* __restrict__ out){
    int wave = threadIdx.x>>6, lane = threadIdx.x&63;
    int m = lane&15, quad = lane>>4;
    int n = blockIdx.y;
    int rowbase = blockIdx.x*256 + wave*64;
    short8 wl[2][4], la[4][2];
    #pragma unroll
    for (int c=0;c<4;++c){
        #pragma unroll
        for (int s=0;s<2;++s){
            wl[s][c] = *(const short8*)(wloc + n*4096 + (c*16+m)*64 + s*32 + quad*8);
            la[c][s] = *(const short8*)(lrA + (size_t)(n*64 + c*16 + m)*64 + s*32 + quad*8);
        }
    }
    #pragma unroll
    for (int tile=0; tile<4; ++tile){
        int r0 = rowbase + tile*16;
        const ushort_t* lb = rlow + (size_t)(r0+m)*64 + quad*8;
        short8 al0 = *(const short8*)lb;
        short8 al1 = *(const short8*)(lb + 32);
        const ushort_t* ab = r + (size_t)(r0+m)*D_ + n*64 + quad*8;
        short8 ar0 = *(const short8*)ab;
        short8 ar1 = *(const short8*)(ab + 32);
        f32x4 acc[4];
        #pragma unroll
        for (int c=0;c<4;++c){
            acc[c]=(f32x4)0.f;
            acc[c]=mfma16(al0, la[c][0], acc[c]);
            acc[c]=mfma16(al1, la[c][1], acc[c]);
            acc[c]=mfma16(ar0, wl[0][c], acc[c]);
            acc[c]=mfma16(ar1, wl[1][c], acc[c]);
        }
        #pragma unroll
        for (int c=0;c<4;++c){
            int col = n*64 + c*16 + m;
            #pragma unroll
            for (int r2=0;r2<4;++r2){
                size_t idx = (size_t)(r0 + quad*4 + r2)*D_ + col;
                out[idx] = x[idx] + acc[c][r2];
            }
        }
    }
}

extern "C" void kernel_launch(void* const* d_in, const int* in_sizes, int n_in,
                              void* d_out, int out_size, void* d_ws, size_t ws_size,
                              hipStream_t stream) {
    const float* x         = (const float*)d_in[0];
    const int*   active_k  = (const int*)  d_in[1];
    const float* b_seq_w   = (const float*)d_in[2];
    const float* b_depth_w = (const float*)d_in[3];
    const float* w_post_w  = (const float*)d_in[4];
    const float* w_local_w = (const float*)d_in[5];
    const float* lr_A      = (const float*)d_in[6];
    const float* lr_B      = (const float*)d_in[7];
    const float* logA_seq  = (const float*)d_in[8];
    const float* logdt_seq = (const float*)d_in[9];
    const float* logA_dep  = (const float*)d_in[10];
    const float* logdt_dep = (const float*)d_in[11];

    float* ws    = (float*)d_ws;
    float* carry = ws;                               // B_*NCH_*D_ = 262144
    float* aseq  = carry + (size_t)B_*NCH_*D_;
    float* apowC = aseq + D_;
    float* gain  = apowC + D_;
    float* sumsq = gain + D_;                        // R_
    float* rowscale = sumsq + R_;                    // R_
    ushort_t* ub       = (ushort_t*)(rowscale + R_);
    ushort_t* e_bf     = ub;                         // R_*D_
    ushort_t* drive_bf = e_bf + (size_t)R_*D_;       // R_*D_
    ushort_t* hdep_bf  = drive_bf + (size_t)R_*D_;   // R_*D_
    ushort_t* h_bf     = hdep_bf + (size_t)R_*D_;    // R_*D_
    ushort_t* r_bf     = h_bf + (size_t)R_*D_;       // R_*D_
    ushort_t* rlow_bf  = r_bf + (size_t)R_*D_;       // R_*64
    ushort_t* wseq_bf  = rlow_bf + (size_t)R_*64;    // 65536
    ushort_t* wdep_bf  = wseq_bf + 65536;
    ushort_t* wpost_bf = wdep_bf + 65536;            // 196608
    ushort_t* wloc_bf  = wpost_bf + 196608;
    ushort_t* lrA_bf   = wloc_bf + 65536;
    ushort_t* lrB_bf   = lrA_bf + 65536;

    setup_k<<<4, 256, 0, stream>>>(logA_seq, logdt_seq, logA_dep, logdt_dep, active_k,
                                   aseq, apowC, gain);
    cvt6_k<<<524288/256, 256, 0, stream>>>(b_seq_w, b_depth_w, w_post_w, w_local_w, lr_A, lr_B,
                                           wseq_bf, wdep_bf, wpost_bf, wloc_bf, lrA_bf, lrB_bf);
    hipMemsetAsync(sumsq, 0, R_*sizeof(float), stream);

    rmsbf_k<<<R_, 256, 0, stream>>>(x, e_bf);
    bd2_k  <<<dim3(R_/256, 16), 256, 0, stream>>>(e_bf, wseq_bf, wdep_bf, gain, drive_bf, hdep_bf);
    scan1_k<<<(B_*NCH_*D_)/256, 256, 0, stream>>>(drive_bf, aseq, carry);
    scan2_k<<<(B_*D_)/256, 256, 0, stream>>>(carry, apowC);
    scan3_k<<<(B_*NCH_*D_)/256, 256, 0, stream>>>(drive_bf, hdep_bf, aseq, carry, h_bf, sumsq);
    rowscale_k<<<R_/256, 256, 0, stream>>>(sumsq, rowscale);
    post_k <<<dim3(R_/256, 16), 256, 0, stream>>>(h_bf, rowscale, e_bf, wpost_bf, r_bf);
    rlow_k <<<R_/64, 256, 0, stream>>>(r_bf, lrB_bf, rlow_bf);
    out_k  <<<dim3(R_/256, 16), 256, 0, stream>>>(x, r_bf, rlow_bf, wloc_bf, lrA_bf, (float*)d_out);
}

// Round 5
// 356.830 us; speedup vs baseline: 4.6575x; 1.0009x over previous
//
#include <hip/hip_runtime.h>

#define B_ 4
#define T_ 4096
#define D_ 1024
#define R_ (B_*T_)
#define CHUNK_ 64
#define NCH_ (T_/CHUNK_)
#define EPS_ 1.1920929e-07f

typedef unsigned short ushort_t;
typedef __attribute__((ext_vector_type(8))) short short8;
typedef __attribute__((ext_vector_type(4))) float f32x4;

__device__ __forceinline__ float silu_f(float v){ return v / (1.0f + expf(-v)); }

__device__ __forceinline__ ushort_t f2bf(float f){
    unsigned u = __float_as_uint(f);
    unsigned r = u + 0x7fffu + ((u>>16)&1u);
    return (ushort_t)(r>>16);
}
__device__ __forceinline__ float bf2f(ushort_t s){ return __uint_as_float(((unsigned)s)<<16); }

__device__ __forceinline__ f32x4 mfma16(short8 a, short8 b, f32x4 c){
    return __builtin_amdgcn_mfma_f32_16x16x32_bf16(a, b, c, 0, 0, 0);
}

__device__ __forceinline__ short8 scale_bf8(short8 raw, float sc){
    short8 o;
    #pragma unroll
    for (int j=0;j<8;++j) o[j] = (short)f2bf(bf2f((ushort_t)raw[j]) * sc);
    return o;
}

// ---------------- prep: weight cvt (bf16) + scalar setup ----------------
__global__ void prep_k(const float* __restrict__ s0, const float* __restrict__ s1,
                       const float* __restrict__ s2, const float* __restrict__ s3,
                       const float* __restrict__ s4, const float* __restrict__ s5,
                       ushort_t* __restrict__ d0, ushort_t* __restrict__ d1,
                       ushort_t* __restrict__ d2, ushort_t* __restrict__ d3,
                       ushort_t* __restrict__ d4, ushort_t* __restrict__ d5,
                       const float* __restrict__ logA_seq, const float* __restrict__ logdt_seq,
                       const float* __restrict__ logA_dep, const float* __restrict__ logdt_dep,
                       const int* __restrict__ active_k,
                       float* __restrict__ aseq, float* __restrict__ apowC, float* __restrict__ gain){
    int i = blockIdx.x*256 + threadIdx.x;
    if      (i < 65536)   d0[i] = f2bf(s0[i]);
    else if (i < 131072)  d1[i-65536] = f2bf(s1[i-65536]);
    else if (i < 327680)  d2[i-131072] = f2bf(s2[i-131072]);
    else if (i < 393216)  d3[i-327680] = f2bf(s3[i-327680]);
    else if (i < 458752)  d4[i-393216] = f2bf(s4[i-393216]);
    else if (i < 524288)  d5[i-458752] = f2bf(s5[i-458752]);
    else if (i < 524288 + D_){
        int d = i - 524288;
        float K = (float)(*active_k);
        float a = expf(-expf(logA_seq[d]) * expf(logdt_seq[d]));
        a = fmaxf(a, 1e-6f);
        aseq[d] = a;
        apowC[d] = powf(a, (float)CHUNK_);
        float g;
        if (d < 128) {
            g = K;
        } else {
            float ad = expf(-expf(logA_dep[d-128]) * expf(logdt_dep[d-128]));
            float om = 1.0f - ad;
            if (fabsf(om) < 1e-6f) g = K;
            else g = (1.0f - powf(ad, K)) / fmaxf(om, 1e-8f);
        }
        gain[d] = g;
    }
}

// ---------------- rms_norm(x) -> e bf16 ----------------
__global__ __launch_bounds__(256) void rmsbf_k(const float* __restrict__ x, ushort_t* __restrict__ e){
    int row = blockIdx.x;
    int tid = threadIdx.x;
    float4 v = ((const float4*)(x + (size_t)row*D_))[tid];
    float ss = v.x*v.x + v.y*v.y + v.z*v.z + v.w*v.w;
    for (int off=32; off; off>>=1) ss += __shfl_down(ss, off, 64);
    __shared__ float red[4];
    if ((tid&63)==0) red[tid>>6] = ss;
    __syncthreads();
    float tot = red[0]+red[1]+red[2]+red[3];
    float scale = 1.0f / sqrtf(tot*(1.0f/D_) + EPS_);
    ushort4 o;
    o.x = f2bf(v.x*scale); o.y = f2bf(v.y*scale); o.z = f2bf(v.z*scale); o.w = f2bf(v.w*scale);
    ((ushort4*)(e + (size_t)row*D_))[tid] = o;
}

// ---------------- bd2: drive=silu(e@Wseq^T), hdep=gain*silu(e@Wdep^T), both bf16 ----------------
__global__ __launch_bounds__(256) void bd2_k(const ushort_t* __restrict__ e,
        const ushort_t* __restrict__ wseq, const ushort_t* __restrict__ wdep,
        const float* __restrict__ gain,
        ushort_t* __restrict__ drive, ushort_t* __restrict__ hdep){
    __shared__ __align__(16) ushort_t st[2][4][16][72];
    int wave = threadIdx.x>>6, lane = threadIdx.x&63;
    int m = lane&15, quad = lane>>4;
    int n = blockIdx.y;
    int r0 = blockIdx.x*64 + wave*16;
    int orow = lane>>2, oq = lane&3;

    short8 bs[2][4], bd[2][4];
    #pragma unroll
    for (int s=0;s<2;++s)
        #pragma unroll
        for (int c=0;c<4;++c){
            bs[s][c] = *(const short8*)(wseq + n*4096 + (c*16+m)*64 + s*32 + quad*8);
            bd[s][c] = *(const short8*)(wdep + n*4096 + (c*16+m)*64 + s*32 + quad*8);
        }
    float g[4];
    #pragma unroll
    for (int c=0;c<4;++c) g[c] = gain[n*64 + c*16 + m];

    const ushort_t* ab = e + (size_t)(r0+m)*D_ + n*64 + quad*8;
    short8 a0 = *(const short8*)ab;
    short8 a1 = *(const short8*)(ab + 32);
    f32x4 accs[4], accd[4];
    #pragma unroll
    for (int c=0;c<4;++c){
        accs[c]=(f32x4)0.f; accd[c]=(f32x4)0.f;
        accs[c]=mfma16(a0, bs[0][c], accs[c]);
        accd[c]=mfma16(a0, bd[0][c], accd[c]);
        accs[c]=mfma16(a1, bs[1][c], accs[c]);
        accd[c]=mfma16(a1, bd[1][c], accd[c]);
    }
    #pragma unroll
    for (int c=0;c<4;++c)
        #pragma unroll
        for (int r=0;r<4;++r){
            st[0][wave][quad*4+r][c*16+m] = f2bf(silu_f(accs[c][r]));
            st[1][wave][quad*4+r][c*16+m] = f2bf(g[c] * silu_f(accd[c][r]));
        }
    __syncthreads();
    ushort_t* db = drive + (size_t)(r0+orow)*D_ + n*64;
    ushort_t* hb = hdep  + (size_t)(r0+orow)*D_ + n*64;
    #pragma unroll
    for (int it=0;it<2;++it){
        *(short8*)(db + (it*4+oq)*8) = *(const short8*)&st[0][wave][orow][(it*4+oq)*8];
        *(short8*)(hb + (it*4+oq)*8) = *(const short8*)&st[1][wave][orow][(it*4+oq)*8];
    }
}

// ---------------- scan1: chunk-final sums ----------------
__global__ __launch_bounds__(256) void scan1_k(const ushort_t* __restrict__ drive,
                                               const float* __restrict__ aseq,
                                               float* __restrict__ carry){
    int tid = blockIdx.x*256 + threadIdx.x;
    int d  = tid & (D_-1);
    int bc = tid >> 10;
    int c  = bc & (NCH_-1);
    int b  = bc >> 6;
    float a = aseq[d];
    size_t base = ((size_t)(b*T_ + c*CHUNK_))*D_ + d;
    float hh = 0.f;
    #pragma unroll 4
    for (int s=0; s<CHUNK_; ++s)
        hh = fmaf(a, hh, bf2f(drive[base + (size_t)s*D_]));
    carry[(size_t)bc*D_ + d] = hh;
}

// ---------------- scan2: serial prefix over chunk carries ----------------
__global__ __launch_bounds__(256) void scan2_k(float* __restrict__ carry, const float* __restrict__ apowC){
    int tid = blockIdx.x*256 + threadIdx.x;
    int d = tid & (D_-1);
    int b = tid >> 10;
    float aC = apowC[d];
    float pref = 0.f;
    for (int c=0;c<NCH_;++c){
        size_t idx = (size_t)(b*NCH_+c)*D_ + d;
        float s = carry[idx];
        carry[idx] = pref;
        pref = fmaf(aC, pref, s);
    }
}

// ---------------- scan3: recompute local scan + carry + hdep -> h bf16 ----------------
__global__ __launch_bounds__(256) void scan3_k(const ushort_t* __restrict__ drive,
                                               const ushort_t* __restrict__ hdep,
                                               const float* __restrict__ aseq,
                                               const float* __restrict__ carry,
                                               ushort_t* __restrict__ h){
    int tid = blockIdx.x*256 + threadIdx.x;
    int d  = tid & (D_-1);
    int bc = tid >> 10;
    int c  = bc & (NCH_-1);
    int b  = bc >> 6;
    float a = aseq[d];
    float hh = carry[(size_t)bc*D_ + d];
    size_t base = ((size_t)(b*T_ + c*CHUNK_))*D_ + d;
    #pragma unroll 4
    for (int s=0; s<CHUNK_; ++s){
        size_t idx = base + (size_t)s*D_;
        hh = fmaf(a, hh, bf2f(drive[idx]));
        h[idx] = f2bf(hh + bf2f(hdep[idx]));
    }
}

// ---------------- rowscale = rsqrt(mean(h^2)+eps) per row ----------------
__global__ __launch_bounds__(128) void rowscale_k(const ushort_t* __restrict__ h, float* __restrict__ rowscale){
    int row = blockIdx.x;
    int tid = threadIdx.x;
    short8 v = *(const short8*)(h + (size_t)row*D_ + tid*8);
    float ss = 0.f;
    #pragma unroll
    for (int j=0;j<8;++j){ float f = bf2f((ushort_t)v[j]); ss += f*f; }
    for (int off=32; off; off>>=1) ss += __shfl_down(ss, off, 64);
    __shared__ float red[2];
    if ((tid&63)==0) red[tid>>6] = ss;
    __syncthreads();
    if (tid==0){
        float tot = red[0]+red[1];
        rowscale[row] = rsqrtf(tot*(1.0f/D_) + EPS_);
    }
}

// ---------------- post: r = silu(concat[hn,e,eshift] @ wpost^T) bf16 ----------------
__global__ __launch_bounds__(256) void post_k(const ushort_t* __restrict__ h, const float* __restrict__ rowscale,
                                              const ushort_t* __restrict__ e,
                                              const ushort_t* __restrict__ wpost, ushort_t* __restrict__ rout){
    __shared__ __align__(16) ushort_t st[4][16][72];
    int wave = threadIdx.x>>6, lane = threadIdx.x&63;
    int m = lane&15, quad = lane>>4;
    int n = blockIdx.y;
    int r0 = blockIdx.x*64 + wave*16;
    int orow = lane>>2, oq = lane&3;

    short8 bw[6][4];
    #pragma unroll
    for (int s=0;s<6;++s)
        #pragma unroll
        for (int c=0;c<4;++c)
            bw[s][c] = *(const short8*)(wpost + n*(64*192) + (c*16+m)*192 + s*32 + quad*8);

    int row = r0 + m;
    float sc = rowscale[row];
    bool zrow = ((row & (T_-1)) == 0);
    short8 af[6];
    #pragma unroll
    for (int s=0;s<6;++s){
        int g0 = n*192 + s*32;
        if (g0 < 1024){
            short8 raw = *(const short8*)(h + (size_t)row*D_ + g0 + quad*8);
            af[s] = scale_bf8(raw, sc);
        } else if (g0 < 2048){
            af[s] = *(const short8*)(e + (size_t)row*D_ + (g0-1024) + quad*8);
        } else {
            if (zrow) af[s] = short8{0,0,0,0,0,0,0,0};
            else      af[s] = *(const short8*)(e + (size_t)(row-1)*D_ + (g0-2048) + quad*8);
        }
    }
    f32x4 acc[4];
    #pragma unroll
    for (int c=0;c<4;++c) acc[c]=(f32x4)0.f;
    #pragma unroll
    for (int s=0;s<6;++s)
        #pragma unroll
        for (int c=0;c<4;++c)
            acc[c] = mfma16(af[s], bw[s][c], acc[c]);
    #pragma unroll
    for (int c=0;c<4;++c)
        #pragma unroll
        for (int r=0;r<4;++r)
            st[wave][quad*4+r][c*16+m] = f2bf(silu_f(acc[c][r]));
    __syncthreads();
    ushort_t* db = rout + (size_t)(r0+orow)*D_ + n*64;
    #pragma unroll
    for (int it=0;it<2;++it)
        *(short8*)(db + (it*4+oq)*8) = *(const short8*)&st[wave][orow][(it*4+oq)*8];
}

// ---------------- rlow = r @ lrB^T (K=1024 -> 64) bf16 ----------------
__global__ __launch_bounds__(256) void rlow_k(const ushort_t* __restrict__ r, const ushort_t* __restrict__ lrB,
                                              ushort_t* __restrict__ rlow){
    __shared__ __align__(16) ushort_t st[4][16][72];
    int wave = threadIdx.x>>6, lane = threadIdx.x&63;
    int m = lane&15, quad = lane>>4;
    int r0 = (blockIdx.x*4 + wave)*16;
    int orow = lane>>2, oq = lane&3;
    f32x4 acc[4];
    #pragma unroll
    for (int c=0;c<4;++c) acc[c]=(f32x4)0.f;
    const ushort_t* ab = r + (size_t)(r0+m)*D_ + quad*8;
    #pragma unroll 4
    for (int s=0;s<32;++s){
        short8 a = *(const short8*)(ab + s*32);
        #pragma unroll
        for (int c=0;c<4;++c){
            short8 b = *(const short8*)(lrB + (c*16+m)*1024 + s*32 + quad*8);
            acc[c] = mfma16(a, b, acc[c]);
        }
    }
    #pragma unroll
    for (int c=0;c<4;++c)
        #pragma unroll
        for (int r2=0;r2<4;++r2)
            st[wave][quad*4+r2][c*16+m] = f2bf(acc[c][r2]);
    __syncthreads();
    ushort_t* db = rlow + (size_t)(r0+orow)*64;
    #pragma unroll
    for (int it=0;it<2;++it)
        *(short8*)(db + (it*4+oq)*8) = *(const short8*)&st[wave][orow][(it*4+oq)*8];
}

// ---------------- out = x + r@wloc^T + rlow@lrA^T ----------------
__global__ __launch_bounds__(256) void out_k(const float* __restrict__ x, const ushort_t* __restrict__ r,
        const ushort_t* __restrict__ rlow, const ushort_t* __restrict__ wloc, const ushort_t* __restrict__ lrA,
        float* __restrict__ out){
    __shared__ __align__(16) float st[4][16][68];
    int wave = threadIdx.x>>6, lane = threadIdx.x&63;
    int m = lane&15, quad = lane>>4;
    int n = blockIdx.y;
    int r0 = blockIdx.x*64 + wave*16;
    int orow = lane>>2, oq = lane&3;

    // prefetch x (float4, coalesced)
    const float* xb = x + (size_t)(r0+orow)*D_ + n*64;
    float4 xv[4];
    #pragma unroll
    for (int it=0;it<4;++it) xv[it] = *(const float4*)(xb + (it*4+oq)*4);

    short8 wl[2][4], la[4][2];
    #pragma unroll
    for (int c=0;c<4;++c)
        #pragma unroll
        for (int s=0;s<2;++s){
            wl[s][c] = *(const short8*)(wloc + n*4096 + (c*16+m)*64 + s*32 + quad*8);
            la[c][s] = *(const short8*)(lrA + (size_t)(n*64 + c*16 + m)*64 + s*32 + quad*8);
        }
    const ushort_t* lb = rlow + (size_t)(r0+m)*64 + quad*8;
    short8 al0 = *(const short8*)lb;
    short8 al1 = *(const short8*)(lb + 32);
    const ushort_t* ab = r + (size_t)(r0+m)*D_ + n*64 + quad*8;
    short8 ar0 = *(const short8*)ab;
    short8 ar1 = *(const short8*)(ab + 32);
    f32x4 acc[4];
    #pragma unroll
    for (int c=0;c<4;++c){
        acc[c]=(f32x4)0.f;
        acc[c]=mfma16(al0, la[c][0], acc[c]);
        acc[c]=mfma16(al1, la[c][1], acc[c]);
        acc[c]=mfma16(ar0, wl[0][c], acc[c]);
        acc[c]=mfma16(ar1, wl[1][c], acc[c]);
    }
    #pragma unroll
    for (int c=0;c<4;++c)
        #pragma unroll
        for (int r2=0;r2<4;++r2)
            st[wave][quad*4+r2][c*16+m] = acc[c][r2];
    __syncthreads();
    float* ob = out + (size_t)(r0+orow)*D_ + n*64;
    #pragma unroll
    for (int it=0;it<4;++it){
        float4 v = *(const float4*)&st[wave][orow][(it*4+oq)*4];
        v.x += xv[it].x; v.y += xv[it].y; v.z += xv[it].z; v.w += xv[it].w;
        *(float4*)(ob + (it*4+oq)*4) = v;
    }
}

extern "C" void kernel_launch(void* const* d_in, const int* in_sizes, int n_in,
                              void* d_out, int out_size, void* d_ws, size_t ws_size,
                              hipStream_t stream) {
    const float* x         = (const float*)d_in[0];
    const int*   active_k  = (const int*)  d_in[1];
    const float* b_seq_w   = (const float*)d_in[2];
    const float* b_depth_w = (const float*)d_in[3];
    const float* w_post_w  = (const float*)d_in[4];
    const float* w_local_w = (const float*)d_in[5];
    const float* lr_A      = (const float*)d_in[6];
    const float* lr_B      = (const float*)d_in[7];
    const float* logA_seq  = (const float*)d_in[8];
    const float* logdt_seq = (const float*)d_in[9];
    const float* logA_dep  = (const float*)d_in[10];
    const float* logdt_dep = (const float*)d_in[11];

    float* ws    = (float*)d_ws;
    float* carry = ws;                               // B_*NCH_*D_ = 262144
    float* aseq  = carry + (size_t)B_*NCH_*D_;
    float* apowC = aseq + D_;
    float* gain  = apowC + D_;
    float* rowscale = gain + D_;                     // R_
    ushort_t* ub       = (ushort_t*)(rowscale + R_);
    ushort_t* e_bf     = ub;                         // R_*D_
    ushort_t* drive_bf = e_bf + (size_t)R_*D_;       // R_*D_
    ushort_t* hdep_bf  = drive_bf + (size_t)R_*D_;   // R_*D_
    ushort_t* h_bf     = hdep_bf + (size_t)R_*D_;    // R_*D_
    ushort_t* r_bf     = h_bf + (size_t)R_*D_;       // R_*D_
    ushort_t* rlow_bf  = r_bf + (size_t)R_*D_;       // R_*64
    ushort_t* wseq_bf  = rlow_bf + (size_t)R_*64;    // 65536
    ushort_t* wdep_bf  = wseq_bf + 65536;
    ushort_t* wpost_bf = wdep_bf + 65536;            // 196608
    ushort_t* wloc_bf  = wpost_bf + 196608;
    ushort_t* lrA_bf   = wloc_bf + 65536;
    ushort_t* lrB_bf   = lrA_bf + 65536;

    prep_k<<<(524288 + D_ + 255)/256, 256, 0, stream>>>(
        b_seq_w, b_depth_w, w_post_w, w_local_w, lr_A, lr_B,
        wseq_bf, wdep_bf, wpost_bf, wloc_bf, lrA_bf, lrB_bf,
        logA_seq, logdt_seq, logA_dep, logdt_dep, active_k, aseq, apowC, gain);

    rmsbf_k<<<R_, 256, 0, stream>>>(x, e_bf);
    bd2_k  <<<dim3(R_/64, 16), 256, 0, stream>>>(e_bf, wseq_bf, wdep_bf, gain, drive_bf, hdep_bf);
    scan1_k<<<(B_*NCH_*D_)/256, 256, 0, stream>>>(drive_bf, aseq, carry);
    scan2_k<<<(B_*D_)/256, 256, 0, stream>>>(carry, apowC);
    scan3_k<<<(B_*NCH_*D_)/256, 256, 0, stream>>>(drive_bf, hdep_bf, aseq, carry, h_bf);
    rowscale_k<<<R_, 128, 0, stream>>>(h_bf, rowscale);
    post_k <<<dim3(R_/64, 16), 256, 0, stream>>>(h_bf, rowscale, e_bf, wpost_bf, r_bf);
    rlow_k <<<R_/64, 256, 0, stream>>>(r_bf, lrB_bf, rlow_bf);
    out_k  <<<dim3(R_/64, 16), 256, 0, stream>>>(x, r_bf, rlow_bf, wloc_bf, lrA_bf, (float*)d_out);
}

// Round 6
// 303.914 us; speedup vs baseline: 5.4684x; 1.1741x over previous
//
#include <hip/hip_runtime.h>

#define B_ 4
#define T_ 4096
#define D_ 1024
#define R_ (B_*T_)
#define CHUNK_ 64
#define NCH_ (T_/CHUNK_)
#define EPS_ 1.1920929e-07f

typedef unsigned short ushort_t;
typedef __attribute__((ext_vector_type(8))) short short8;
typedef __attribute__((ext_vector_type(4))) float f32x4;

__device__ __forceinline__ float silu_f(float v){ return v / (1.0f + __expf(-v)); }

__device__ __forceinline__ ushort_t f2bf(float f){
    unsigned u = __float_as_uint(f);
    unsigned r = u + 0x7fffu + ((u>>16)&1u);
    return (ushort_t)(r>>16);
}
__device__ __forceinline__ float bf2f(ushort_t s){ return __uint_as_float(((unsigned)s)<<16); }

__device__ __forceinline__ f32x4 mfma16(short8 a, short8 b, f32x4 c){
    return __builtin_amdgcn_mfma_f32_16x16x32_bf16(a, b, c, 0, 0, 0);
}

// ---------------- prep: weight cvt (bf16) + scalar setup ----------------
__global__ void prep_k(const float* __restrict__ s0, const float* __restrict__ s1,
                       const float* __restrict__ s2, const float* __restrict__ s3,
                       const float* __restrict__ s4, const float* __restrict__ s5,
                       ushort_t* __restrict__ d0, ushort_t* __restrict__ d1,
                       ushort_t* __restrict__ d2, ushort_t* __restrict__ d3,
                       ushort_t* __restrict__ d4, ushort_t* __restrict__ d5,
                       const float* __restrict__ logA_seq, const float* __restrict__ logdt_seq,
                       const float* __restrict__ logA_dep, const float* __restrict__ logdt_dep,
                       const int* __restrict__ active_k,
                       float* __restrict__ aseq, float* __restrict__ apowC, float* __restrict__ gain){
    int i = blockIdx.x*256 + threadIdx.x;
    if      (i < 65536)   d0[i] = f2bf(s0[i]);
    else if (i < 131072)  d1[i-65536] = f2bf(s1[i-65536]);
    else if (i < 327680)  d2[i-131072] = f2bf(s2[i-131072]);
    else if (i < 393216)  d3[i-327680] = f2bf(s3[i-327680]);
    else if (i < 458752)  d4[i-393216] = f2bf(s4[i-393216]);
    else if (i < 524288)  d5[i-458752] = f2bf(s5[i-458752]);
    else if (i < 524288 + D_){
        int d = i - 524288;
        float K = (float)(*active_k);
        float a = expf(-expf(logA_seq[d]) * expf(logdt_seq[d]));
        a = fmaxf(a, 1e-6f);
        aseq[d] = a;
        apowC[d] = powf(a, (float)CHUNK_);
        float g;
        if (d < 128) {
            g = K;
        } else {
            float ad = expf(-expf(logA_dep[d-128]) * expf(logdt_dep[d-128]));
            float om = 1.0f - ad;
            if (fabsf(om) < 1e-6f) g = K;
            else g = (1.0f - powf(ad, K)) / fmaxf(om, 1e-8f);
        }
        gain[d] = g;
    }
}

// ---------------- rms_norm(x) -> e bf16 ----------------
__global__ __launch_bounds__(256) void rmsbf_k(const float* __restrict__ x, ushort_t* __restrict__ e){
    int row = blockIdx.x;
    int tid = threadIdx.x;
    float4 v = ((const float4*)(x + (size_t)row*D_))[tid];
    float ss = v.x*v.x + v.y*v.y + v.z*v.z + v.w*v.w;
    for (int off=32; off; off>>=1) ss += __shfl_down(ss, off, 64);
    __shared__ float red[4];
    if ((tid&63)==0) red[tid>>6] = ss;
    __syncthreads();
    float tot = red[0]+red[1]+red[2]+red[3];
    float scale = 1.0f / sqrtf(tot*(1.0f/D_) + EPS_);
    ushort4 o;
    o.x = f2bf(v.x*scale); o.y = f2bf(v.y*scale); o.z = f2bf(v.z*scale); o.w = f2bf(v.w*scale);
    ((ushort4*)(e + (size_t)row*D_))[tid] = o;
}

// ---------------- bd2s: drive/hdep blockdiags + fused local chunk scan ----------------
// block = 256 rows x one n-block; each wave owns a 64-row chunk (== CHUNK_)
__global__ __launch_bounds__(256) void bd2s_k(const ushort_t* __restrict__ e,
        const ushort_t* __restrict__ wseq, const ushort_t* __restrict__ wdep,
        const float* __restrict__ gain, const float* __restrict__ aseq,
        ushort_t* __restrict__ hloc, ushort_t* __restrict__ hdep, float* __restrict__ carry){
    __shared__ __align__(16) ushort_t sd[4][64][72];   // drive tiles, wave-private
    __shared__ __align__(16) ushort_t sh[4][16][72];   // hdep tile, wave-private
    int wave = threadIdx.x>>6, lane = threadIdx.x&63;
    int m = lane&15, quad = lane>>4;
    int orow = lane>>2, oq = lane&3;
    int n = blockIdx.y;
    int chunk0 = blockIdx.x*256 + wave*64;

    short8 bs[2][4], bd[2][4];
    #pragma unroll
    for (int s=0;s<2;++s)
        #pragma unroll
        for (int c=0;c<4;++c){
            bs[s][c] = *(const short8*)(wseq + n*4096 + (c*16+m)*64 + s*32 + quad*8);
            bd[s][c] = *(const short8*)(wdep + n*4096 + (c*16+m)*64 + s*32 + quad*8);
        }
    float g[4];
    #pragma unroll
    for (int c=0;c<4;++c) g[c] = gain[n*64 + c*16 + m];

    #pragma unroll
    for (int t=0;t<4;++t){
        int r0 = chunk0 + t*16;
        const ushort_t* ab = e + (size_t)(r0+m)*D_ + n*64 + quad*8;
        short8 a0 = *(const short8*)ab;
        short8 a1 = *(const short8*)(ab + 32);
        f32x4 accs[4], accd[4];
        #pragma unroll
        for (int c=0;c<4;++c){
            accs[c]=(f32x4)0.f; accd[c]=(f32x4)0.f;
            accs[c]=mfma16(a0, bs[0][c], accs[c]);
            accd[c]=mfma16(a0, bd[0][c], accd[c]);
            accs[c]=mfma16(a1, bs[1][c], accs[c]);
            accd[c]=mfma16(a1, bd[1][c], accd[c]);
        }
        #pragma unroll
        for (int c=0;c<4;++c)
            #pragma unroll
            for (int r=0;r<4;++r){
                sd[wave][t*16+quad*4+r][c*16+m] = f2bf(silu_f(accs[c][r]));
                sh[wave][quad*4+r][c*16+m]      = f2bf(g[c]*silu_f(accd[c][r]));
            }
        // hdep store (wave-private LDS -> no barrier needed)
        ushort_t* hb = hdep + (size_t)(r0+orow)*D_ + n*64;
        #pragma unroll
        for (int it=0;it<2;++it)
            *(short8*)(hb + (it*4+oq)*8) = *(const short8*)&sh[wave][orow][(it*4+oq)*8];
    }
    // local serial scan along the wave's 64 rows, one column per lane
    float a = aseq[n*64 + lane];
    float hh = 0.f;
    #pragma unroll 8
    for (int s=0;s<64;++s){
        hh = fmaf(a, hh, bf2f(sd[wave][s][lane]));
        sd[wave][s][lane] = f2bf(hh);
    }
    carry[(size_t)(chunk0>>6)*D_ + n*64 + lane] = hh;
    // store locally-scanned h'
    #pragma unroll
    for (int t=0;t<4;++t){
        ushort_t* db = hloc + (size_t)(chunk0 + t*16 + orow)*D_ + n*64;
        #pragma unroll
        for (int it=0;it<2;++it)
            *(short8*)(db + (it*4+oq)*8) = *(const short8*)&sd[wave][t*16+orow][(it*4+oq)*8];
    }
}

// ---------------- scan2: serial prefix over chunk carries ----------------
__global__ __launch_bounds__(256) void scan2_k(float* __restrict__ carry, const float* __restrict__ apowC){
    int tid = blockIdx.x*256 + threadIdx.x;      // B_*D_ threads
    int d = tid & (D_-1);
    int b = tid >> 10;
    float aC = apowC[d];
    float pref = 0.f;
    for (int c=0;c<NCH_;++c){
        size_t idx = (size_t)(b*NCH_+c)*D_ + d;
        float s = carry[idx];
        carry[idx] = pref;
        pref = fmaf(aC, pref, s);
    }
}

// ---------------- scan3: h = h' + P*a^(s+1) + hdep -> bf16 ----------------
__global__ __launch_bounds__(256) void scan3_k(const ushort_t* __restrict__ hloc,
                                               const ushort_t* __restrict__ hdep,
                                               const float* __restrict__ aseq,
                                               const float* __restrict__ carry,
                                               ushort_t* __restrict__ h){
    int tid = blockIdx.x*256 + threadIdx.x;
    int d  = tid & (D_-1);
    int bc = tid >> 10;
    int c  = bc & (NCH_-1);
    int b  = bc >> 6;
    float a = aseq[d];
    float P = carry[(size_t)bc*D_ + d];
    size_t base = ((size_t)(b*T_ + c*CHUNK_))*D_ + d;
    float apow = a;
    #pragma unroll 4
    for (int s=0; s<CHUNK_; ++s){
        size_t idx = base + (size_t)s*D_;
        h[idx] = f2bf(bf2f(hloc[idx]) + P*apow + bf2f(hdep[idx]));
        apow *= a;
    }
}

// ---------------- hn = h * rsqrt(mean(h^2)+eps), bf16 ----------------
__global__ __launch_bounds__(128) void hn_k(const ushort_t* __restrict__ h, ushort_t* __restrict__ hn){
    int row = blockIdx.x;
    int tid = threadIdx.x;
    short8 v = *(const short8*)(h + (size_t)row*D_ + tid*8);
    float f[8];
    float ss = 0.f;
    #pragma unroll
    for (int j=0;j<8;++j){ f[j] = bf2f((ushort_t)v[j]); ss += f[j]*f[j]; }
    for (int off=32; off; off>>=1) ss += __shfl_down(ss, off, 64);
    __shared__ float red[2];
    if ((tid&63)==0) red[tid>>6] = ss;
    __syncthreads();
    float scale = rsqrtf((red[0]+red[1])*(1.0f/D_) + EPS_);
    short8 o;
    #pragma unroll
    for (int j=0;j<8;++j) o[j] = (short)f2bf(f[j]*scale);
    *(short8*)(hn + (size_t)row*D_ + tid*8) = o;
}

// ---------------- post: r = silu(concat[hn,e,eshift] @ wpost^T) bf16 ----------------
__global__ __launch_bounds__(256) void post_k(const ushort_t* __restrict__ hn,
                                              const ushort_t* __restrict__ e,
                                              const ushort_t* __restrict__ wpost, ushort_t* __restrict__ rout){
    __shared__ __align__(16) ushort_t st[4][16][72];
    int wave = threadIdx.x>>6, lane = threadIdx.x&63;
    int m = lane&15, quad = lane>>4;
    int orow = lane>>2, oq = lane&3;
    int n = blockIdx.y;

    short8 bw[6][4];
    #pragma unroll
    for (int s=0;s<6;++s)
        #pragma unroll
        for (int c=0;c<4;++c)
            bw[s][c] = *(const short8*)(wpost + n*(64*192) + (c*16+m)*192 + s*32 + quad*8);

    #pragma unroll
    for (int t=0;t<4;++t){
        int r0 = blockIdx.x*256 + wave*64 + t*16;
        int row = r0 + m;
        bool zrow = ((row & (T_-1)) == 0);
        short8 af[6];
        #pragma unroll
        for (int s=0;s<6;++s){
            int g0 = n*192 + s*32;
            if (g0 < 1024){
                af[s] = *(const short8*)(hn + (size_t)row*D_ + g0 + quad*8);
            } else if (g0 < 2048){
                af[s] = *(const short8*)(e + (size_t)row*D_ + (g0-1024) + quad*8);
            } else {
                if (zrow) af[s] = short8{0,0,0,0,0,0,0,0};
                else      af[s] = *(const short8*)(e + (size_t)(row-1)*D_ + (g0-2048) + quad*8);
            }
        }
        f32x4 acc[4];
        #pragma unroll
        for (int c=0;c<4;++c) acc[c]=(f32x4)0.f;
        #pragma unroll
        for (int s=0;s<6;++s)
            #pragma unroll
            for (int c=0;c<4;++c)
                acc[c] = mfma16(af[s], bw[s][c], acc[c]);
        #pragma unroll
        for (int c=0;c<4;++c)
            #pragma unroll
            for (int r=0;r<4;++r)
                st[wave][quad*4+r][c*16+m] = f2bf(silu_f(acc[c][r]));
        ushort_t* db = rout + (size_t)(r0+orow)*D_ + n*64;
        #pragma unroll
        for (int it=0;it<2;++it)
            *(short8*)(db + (it*4+oq)*8) = *(const short8*)&st[wave][orow][(it*4+oq)*8];
    }
}

// ---------------- rlow = r @ lrB^T (K=1024 -> 64) bf16 ----------------
__global__ __launch_bounds__(256) void rlow_k(const ushort_t* __restrict__ r, const ushort_t* __restrict__ lrB,
                                              ushort_t* __restrict__ rlow){
    __shared__ __align__(16) ushort_t st[4][16][72];
    int wave = threadIdx.x>>6, lane = threadIdx.x&63;
    int m = lane&15, quad = lane>>4;
    int orow = lane>>2, oq = lane&3;
    int r0 = (blockIdx.x*4 + wave)*16;
    f32x4 acc[4];
    #pragma unroll
    for (int c=0;c<4;++c) acc[c]=(f32x4)0.f;
    const ushort_t* ab = r + (size_t)(r0+m)*D_ + quad*8;
    #pragma unroll 4
    for (int s=0;s<32;++s){
        short8 a = *(const short8*)(ab + s*32);
        #pragma unroll
        for (int c=0;c<4;++c){
            short8 b = *(const short8*)(lrB + (c*16+m)*1024 + s*32 + quad*8);
            acc[c] = mfma16(a, b, acc[c]);
        }
    }
    #pragma unroll
    for (int c=0;c<4;++c)
        #pragma unroll
        for (int r2=0;r2<4;++r2)
            st[wave][quad*4+r2][c*16+m] = f2bf(acc[c][r2]);
    ushort_t* db = rlow + (size_t)(r0+orow)*64;
    #pragma unroll
    for (int it=0;it<2;++it)
        *(short8*)(db + (it*4+oq)*8) = *(const short8*)&st[wave][orow][(it*4+oq)*8];
}

// ---------------- out = x + r@wloc^T + rlow@lrA^T ----------------
__global__ __launch_bounds__(256) void out_k(const float* __restrict__ x, const ushort_t* __restrict__ r,
        const ushort_t* __restrict__ rlow, const ushort_t* __restrict__ wloc, const ushort_t* __restrict__ lrA,
        float* __restrict__ out){
    __shared__ __align__(16) float st[4][16][68];
    int wave = threadIdx.x>>6, lane = threadIdx.x&63;
    int m = lane&15, quad = lane>>4;
    int orow = lane>>2, oq = lane&3;
    int n = blockIdx.y;

    short8 wl[2][4], la[4][2];
    #pragma unroll
    for (int c=0;c<4;++c)
        #pragma unroll
        for (int s=0;s<2;++s){
            wl[s][c] = *(const short8*)(wloc + n*4096 + (c*16+m)*64 + s*32 + quad*8);
            la[c][s] = *(const short8*)(lrA + (size_t)(n*64 + c*16 + m)*64 + s*32 + quad*8);
        }
    #pragma unroll
    for (int t=0;t<4;++t){
        int r0 = blockIdx.x*256 + wave*64 + t*16;
        const float* xb = x + (size_t)(r0+orow)*D_ + n*64;
        float4 xv[4];
        #pragma unroll
        for (int it=0;it<4;++it) xv[it] = *(const float4*)(xb + (it*4+oq)*4);

        const ushort_t* lb = rlow + (size_t)(r0+m)*64 + quad*8;
        short8 al0 = *(const short8*)lb;
        short8 al1 = *(const short8*)(lb + 32);
        const ushort_t* ab = r + (size_t)(r0+m)*D_ + n*64 + quad*8;
        short8 ar0 = *(const short8*)ab;
        short8 ar1 = *(const short8*)(ab + 32);
        f32x4 acc[4];
        #pragma unroll
        for (int c=0;c<4;++c){
            acc[c]=(f32x4)0.f;
            acc[c]=mfma16(al0, la[c][0], acc[c]);
            acc[c]=mfma16(al1, la[c][1], acc[c]);
            acc[c]=mfma16(ar0, wl[0][c], acc[c]);
            acc[c]=mfma16(ar1, wl[1][c], acc[c]);
        }
        #pragma unroll
        for (int c=0;c<4;++c)
            #pragma unroll
            for (int r2=0;r2<4;++r2)
                st[wave][quad*4+r2][c*16+m] = acc[c][r2];
        float* ob = out + (size_t)(r0+orow)*D_ + n*64;
        #pragma unroll
        for (int it=0;it<4;++it){
            float4 v = *(const float4*)&st[wave][orow][(it*4+oq)*4];
            v.x += xv[it].x; v.y += xv[it].y; v.z += xv[it].z; v.w += xv[it].w;
            *(float4*)(ob + (it*4+oq)*4) = v;
        }
    }
}

extern "C" void kernel_launch(void* const* d_in, const int* in_sizes, int n_in,
                              void* d_out, int out_size, void* d_ws, size_t ws_size,
                              hipStream_t stream) {
    const float* x         = (const float*)d_in[0];
    const int*   active_k  = (const int*)  d_in[1];
    const float* b_seq_w   = (const float*)d_in[2];
    const float* b_depth_w = (const float*)d_in[3];
    const float* w_post_w  = (const float*)d_in[4];
    const float* w_local_w = (const float*)d_in[5];
    const float* lr_A      = (const float*)d_in[6];
    const float* lr_B      = (const float*)d_in[7];
    const float* logA_seq  = (const float*)d_in[8];
    const float* logdt_seq = (const float*)d_in[9];
    const float* logA_dep  = (const float*)d_in[10];
    const float* logdt_dep = (const float*)d_in[11];

    float* ws    = (float*)d_ws;
    float* carry = ws;                               // B_*NCH_*D_ = 262144
    float* aseq  = carry + (size_t)B_*NCH_*D_;
    float* apowC = aseq + D_;
    float* gain  = apowC + D_;
    ushort_t* ub       = (ushort_t*)(gain + D_);
    ushort_t* e_bf     = ub;                         // R_*D_
    ushort_t* hloc_bf  = e_bf + (size_t)R_*D_;       // R_*D_  (h' from bd2s; later reused as hn)
    ushort_t* hdep_bf  = hloc_bf + (size_t)R_*D_;    // R_*D_
    ushort_t* h_bf     = hdep_bf + (size_t)R_*D_;    // R_*D_
    ushort_t* r_bf     = h_bf + (size_t)R_*D_;       // R_*D_
    ushort_t* rlow_bf  = r_bf + (size_t)R_*D_;       // R_*64
    ushort_t* wseq_bf  = rlow_bf + (size_t)R_*64;    // 65536
    ushort_t* wdep_bf  = wseq_bf + 65536;
    ushort_t* wpost_bf = wdep_bf + 65536;            // 196608
    ushort_t* wloc_bf  = wpost_bf + 196608;
    ushort_t* lrA_bf   = wloc_bf + 65536;
    ushort_t* lrB_bf   = lrA_bf + 65536;
    ushort_t* hn_bf    = hloc_bf;                    // alias: hloc dead after scan3

    prep_k<<<(524288 + D_ + 255)/256, 256, 0, stream>>>(
        b_seq_w, b_depth_w, w_post_w, w_local_w, lr_A, lr_B,
        wseq_bf, wdep_bf, wpost_bf, wloc_bf, lrA_bf, lrB_bf,
        logA_seq, logdt_seq, logA_dep, logdt_dep, active_k, aseq, apowC, gain);

    rmsbf_k<<<R_, 256, 0, stream>>>(x, e_bf);
    bd2s_k <<<dim3(R_/256, 16), 256, 0, stream>>>(e_bf, wseq_bf, wdep_bf, gain, aseq,
                                                  hloc_bf, hdep_bf, carry);
    scan2_k<<<(B_*D_)/256, 256, 0, stream>>>(carry, apowC);
    scan3_k<<<(B_*NCH_*D_)/256, 256, 0, stream>>>(hloc_bf, hdep_bf, aseq, carry, h_bf);
    hn_k   <<<R_, 128, 0, stream>>>(h_bf, hn_bf);
    post_k <<<dim3(R_/256, 16), 256, 0, stream>>>(hn_bf, e_bf, wpost_bf, r_bf);
    rlow_k <<<R_/64, 256, 0, stream>>>(r_bf, lrB_bf, rlow_bf);
    out_k  <<<dim3(R_/256, 16), 256, 0, stream>>>(x, r_bf, rlow_bf, wloc_bf, lrA_bf, (float*)d_out);
}